// Round 7
// baseline (824.705 us; speedup 1.0000x reference)
//
#include <hip/hip_runtime.h>
#include <math.h>

typedef short short8 __attribute__((ext_vector_type(8)));
typedef float f32x4 __attribute__((ext_vector_type(4)));

#define EPSF 1e-5f

union FragU { uint4 q; unsigned u[4]; short8 v; };

// bf16 truncation pack: (trunc(hi)<<16)|trunc(lo) in one v_perm
__device__ __forceinline__ unsigned pack_trunc2(float lo_val, float hi_val) {
    return __builtin_amdgcn_perm(__float_as_uint(hi_val), __float_as_uint(lo_val), 0x07060302u);
}
__device__ __forceinline__ float trunc_bf(float x) {
    return __uint_as_float(__float_as_uint(x) & 0xFFFF0000u);
}

// Producer/consumer barrier WITHOUT vmcnt drain (global prefetch stays in flight).
// Fenced on BOTH sides (R3-verified correct): pre-asm drains own ds ops; post
// sched_barrier + memory-clobber asm keep consumer ds_reads from hoisting above.
#define LGKM0_BAR() do { \
    asm volatile("s_waitcnt lgkmcnt(0)" ::: "memory"); \
    __builtin_amdgcn_s_barrier(); \
    __builtin_amdgcn_sched_barrier(0); \
    asm volatile("" ::: "memory"); \
} while (0)

// ---------------- LN over 128, writes TRANSPOSED xnT[i][m], m padded to 1792 ----------------
__global__ void ln1_kernel(const float* __restrict__ x, const float* __restrict__ w,
                           const float* __restrict__ b, float* __restrict__ xnT) {
    int r = blockIdx.x;
    int t = threadIdx.x;
    const float* row = x + (size_t)r * 128;
    float v0 = row[t], v1 = row[t + 64];
    float s = v0 + v1, q = v0 * v0 + v1 * v1;
    #pragma unroll
    for (int off = 32; off > 0; off >>= 1) {
        s += __shfl_down(s, off);
        q += __shfl_down(q, off);
    }
    s = __shfl(s, 0); q = __shfl(q, 0);
    float mu = s * (1.f / 128.f);
    float var = q * (1.f / 128.f) - mu * mu;
    float rs = rsqrtf(var + EPSF);
    xnT[(size_t)t * 1792 + r]        = (v0 - mu) * rs * w[t]      + b[t];
    xnT[(size_t)(t + 64) * 1792 + r] = (v1 - mu) * rs * w[t + 64] + b[t + 64];
}

// ---------------- fc1: split-bf16 MFMA. block: m-tile 256 (4 waves x m64), n-tile 128 ----------------
// grid (2, 7, ks1=36). Atomic k-split into h1.  [R6 VERBATIM — verified 739 µs config]
__launch_bounds__(256)
__global__ void fc1_kernel(const float* __restrict__ xnT, const float* __restrict__ coeffs,
                           float* __restrict__ h1, int KS) {
    const int nt = blockIdx.x;
    const int mt = blockIdx.y;
    const int ks = blockIdx.z;
    const int i0 = (ks * 128) / KS, i1 = ((ks + 1) * 128) / KS;
    const int t = threadIdx.x;
    const int wv = t >> 6, ln = t & 63;
    const int q = ln >> 4, col = ln & 15;
    const int mwrow = mt * 256 + wv * 64;

    __shared__ unsigned bhi[128 * 36];
    __shared__ unsigned blo[128 * 36];

    const float* c0 = coeffs;                               // [256][128][300]
    const float* c1 = coeffs + (size_t)256 * 128 * 300;

    f32x4 acc[4][8] = {};

    const int srow = t >> 1;            // staging row 0..127
    const int j0 = (t & 1) * 16;
    const int og = nt * 128 + srow;
    const size_t prow = (size_t)og * 128;

    for (int i = i0; i < i1; ++i) {
        float zu[4];
        #pragma unroll
        for (int mf = 0; mf < 4; ++mf) {
            int m = mwrow + mf * 16 + col;
            zu[mf] = (m < 1568) ? xnT[(size_t)i * 1792 + m] : 0.f;
        }
        const float* p0 = c0 + (prow + i) * 300;
        const float* p1 = c1 + (prow + i) * 300;

        for (int c = 0; c < 10; ++c) {
            __syncthreads();
            {
                unsigned hw[16], lw[16];
                #pragma unroll
                for (int k4 = 0; k4 < 4; ++k4) {
                    int g = c * 32 + j0 + k4 * 4;
                    float w0[4], w1[4];
                    if (g + 4 <= 300) {
                        float4 a = *(const float4*)(p0 + g);
                        float4 bb = *(const float4*)(p1 + g);
                        w0[0]=a.x; w0[1]=a.y; w0[2]=a.z; w0[3]=a.w;
                        w1[0]=bb.x; w1[1]=bb.y; w1[2]=bb.z; w1[3]=bb.w;
                    } else {
                        #pragma unroll
                        for (int e = 0; e < 4; ++e) {
                            int gg = g + e; bool ok = gg < 300;
                            w0[e] = ok ? p0[gg] : 0.f;
                            w1[e] = ok ? p1[gg] : 0.f;
                        }
                    }
                    #pragma unroll
                    for (int e = 0; e < 4; ++e) {
                        hw[k4*4+e] = pack_trunc2(w0[e], w1[e]);
                        lw[k4*4+e] = pack_trunc2(w0[e]-trunc_bf(w0[e]), w1[e]-trunc_bf(w1[e]));
                    }
                }
                int base = srow * 36 + j0;
                *(uint4*)&bhi[base]      = make_uint4(hw[0], hw[1], hw[2], hw[3]);
                *(uint4*)&bhi[base + 4]  = make_uint4(hw[4], hw[5], hw[6], hw[7]);
                *(uint4*)&bhi[base + 8]  = make_uint4(hw[8], hw[9], hw[10], hw[11]);
                *(uint4*)&bhi[base + 12] = make_uint4(hw[12], hw[13], hw[14], hw[15]);
                *(uint4*)&blo[base]      = make_uint4(lw[0], lw[1], lw[2], lw[3]);
                *(uint4*)&blo[base + 4]  = make_uint4(lw[4], lw[5], lw[6], lw[7]);
                *(uint4*)&blo[base + 8]  = make_uint4(lw[8], lw[9], lw[10], lw[11]);
                *(uint4*)&blo[base + 12] = make_uint4(lw[12], lw[13], lw[14], lw[15]);
            }
            __syncthreads();
            #pragma unroll
            for (int h = 0; h < 2; ++h) {
                FragU ah[4], al[4];
                #pragma unroll
                for (int mf = 0; mf < 4; ++mf) {
                    #pragma unroll
                    for (int d = 0; d < 4; ++d) {
                        float kf = (float)(c * 32 + h * 16 + q * 4 + d + 1);
                        float a = zu[mf] * kf;
                        float cv = __cosf(a), sv = __sinf(a);
                        ah[mf].u[d] = pack_trunc2(cv, sv);
                        al[mf].u[d] = pack_trunc2(cv - trunc_bf(cv), sv - trunc_bf(sv));
                    }
                }
                #pragma unroll
                for (int nf = 0; nf < 8; ++nf) {
                    int addr = (nf * 16 + col) * 36 + h * 16 + q * 4;
                    FragU bh, bl;
                    bh.q = *(const uint4*)&bhi[addr];
                    bl.q = *(const uint4*)&blo[addr];
                    #pragma unroll
                    for (int mf = 0; mf < 4; ++mf) {
                        acc[mf][nf] = __builtin_amdgcn_mfma_f32_16x16x32_bf16(ah[mf].v, bh.v, acc[mf][nf], 0, 0, 0);
                        acc[mf][nf] = __builtin_amdgcn_mfma_f32_16x16x32_bf16(ah[mf].v, bl.v, acc[mf][nf], 0, 0, 0);
                        acc[mf][nf] = __builtin_amdgcn_mfma_f32_16x16x32_bf16(al[mf].v, bh.v, acc[mf][nf], 0, 0, 0);
                    }
                }
            }
        }
    }
    // epilogue: atomic k-split accumulation (1568 % 16 == 0 so frag is all-in or all-out)
    #pragma unroll
    for (int mf = 0; mf < 4; ++mf) {
        if (mwrow + mf * 16 >= 1568) continue;
        int mbase = mwrow + mf * 16 + q * 4;
        #pragma unroll
        for (int nf = 0; nf < 8; ++nf) {
            int o = nt * 128 + nf * 16 + col;
            #pragma unroll
            for (int r = 0; r < 4; ++r)
                atomicAdd(&h1[(size_t)(mbase + r) * 256 + o], acc[mf][nf][r]);
        }
    }
}

// ---------------- LN over 256 of (h1 + fc1_bias) -> h1n ----------------
__global__ void ln2_kernel(const float* __restrict__ h1, const float* __restrict__ bias,
                           const float* __restrict__ w, const float* __restrict__ b,
                           float* __restrict__ h1n) {
    int r = blockIdx.x;
    int t = threadIdx.x;
    float v = h1[(size_t)r * 256 + t] + bias[t];
    float s = v, q = v * v;
    #pragma unroll
    for (int off = 32; off > 0; off >>= 1) {
        s += __shfl_down(s, off);
        q += __shfl_down(q, off);
    }
    __shared__ float ss[4], qq[4];
    int wid = t >> 6;
    if ((t & 63) == 0) { ss[wid] = s; qq[wid] = q; }
    __syncthreads();
    float S = ss[0] + ss[1] + ss[2] + ss[3];
    float Q = qq[0] + qq[1] + qq[2] + qq[3];
    float mu = S * (1.f / 256.f);
    float var = Q * (1.f / 256.f) - mu * mu;
    float rs = rsqrtf(var + EPSF);
    h1n[(size_t)r * 256 + t] = (v - mu) * rs * w[t] + b[t];
}

__device__ __forceinline__ void cmul(float& xr, float& xi, float br, float bi) {
    float nr = xr * br - xi * bi;
    float ni = xr * bi + xi * br;
    xr = nr; xi = ni;
}

// ---------------- fc2: bf16 MFMA, PIPELINED + M-SPLIT ----------------
// Block: m-tile 128 (2 waves) x n-tile 128, wave tile 64x64 -> acc[4][4] = 64 AGPR.
// Register budget 64 acc + ~150 arch <= 256 -> keeps 2 waves/SIMD WITH the R3-proven
// pipeline (double-buffered LDS, register prefetch, lgkm-only fenced barrier).
// grid (4 = nt*2+mtl, 8 b, ks2=16) = 512 blocks; atomics halved vs ks2=32.
// Staging (srow/j0/LDS layout/LOAD/PACKSTORE) is byte-identical to the verified kernel.
__launch_bounds__(256, 2)
__global__ void fc2_kernel(const float* __restrict__ h1n, const float* __restrict__ coeffs,
                           float* __restrict__ out, int KS) {
    const int bx  = blockIdx.x;
    const int nt  = bx >> 1;            // n-tile 0..1 (o: 0..127 / 128..195)
    const int mtl = bx & 1;             // m-tile 0..1 (c: 0..127 / 128..255)
    const int b   = blockIdx.y;
    const int ks  = blockIdx.z;
    const int i0 = (ks * 196) / KS, i1 = ((ks + 1) * 196) / KS;
    const int t = threadIdx.x;
    const int wv = t >> 6, ln = t & 63;
    const int q = ln >> 4, col = ln & 15;
    const int wm = wv >> 1, wn = wv & 1; // wave grid 2m x 2n
    const int cwb = mtl * 128 + wm * 64; // this wave's m (channel) base
    const int nwb = wn * 64;             // this wave's n base within block tile

    __shared__ unsigned bs[2][128 * 36];

    const float* d0 = coeffs;                               // [196][196][300]
    const float* d1 = coeffs + (size_t)196 * 196 * 300;

    f32x4 acc[4][4] = {};

    const int srow = t >> 1;            // staging row 0..127 (unchanged)
    const int j0 = (t & 1) * 16;
    const int og = nt * 128 + srow;
    const bool son = (og < 196);
    const size_t prow = (size_t)og * 196;

    float w0[16], w1[16];               // prefetch registers (next 32-g chunk in flight)

    auto LOAD = [&](int i, int c) {
        const float* p0 = d0 + (prow + i) * 300;
        const float* p1 = d1 + (prow + i) * 300;
        #pragma unroll
        for (int k4 = 0; k4 < 4; ++k4) {
            int g = c * 32 + j0 + k4 * 4;
            if (son && g + 4 <= 300) {
                float4 a  = *(const float4*)(p0 + g);
                float4 bb = *(const float4*)(p1 + g);
                w0[k4*4+0]=a.x;  w0[k4*4+1]=a.y;  w0[k4*4+2]=a.z;  w0[k4*4+3]=a.w;
                w1[k4*4+0]=bb.x; w1[k4*4+1]=bb.y; w1[k4*4+2]=bb.z; w1[k4*4+3]=bb.w;
            } else {
                #pragma unroll
                for (int e = 0; e < 4; ++e) {
                    int gg = g + e; bool ok = son && (gg < 300);
                    w0[k4*4+e] = ok ? p0[gg] : 0.f;
                    w1[k4*4+e] = ok ? p1[gg] : 0.f;
                }
            }
        }
    };

    auto PACKSTORE = [&](int buf) {
        unsigned hw[16];
        #pragma unroll
        for (int e = 0; e < 16; ++e) hw[e] = pack_trunc2(w0[e], w1[e]);
        int base = srow * 36 + j0;
        *(uint4*)&bs[buf][base]      = make_uint4(hw[0],  hw[1],  hw[2],  hw[3]);
        *(uint4*)&bs[buf][base + 4]  = make_uint4(hw[4],  hw[5],  hw[6],  hw[7]);
        *(uint4*)&bs[buf][base + 8]  = make_uint4(hw[8],  hw[9],  hw[10], hw[11]);
        *(uint4*)&bs[buf][base + 12] = make_uint4(hw[12], hw[13], hw[14], hw[15]);
    };

    int cur = 0;
    LOAD(i0, 0);                        // prologue prefetch
    for (int i = i0; i < i1; ++i) {
        // per-m recurrence state: R tracks e^{i n x}, n = current multiplier
        float Rc[4], Rs[4], E1c[4], E1s[4], E13c[4], E13s[4];
        #pragma unroll
        for (int mf = 0; mf < 4; ++mf) {
            float x = h1n[((size_t)b * 196 + i) * 256 + cwb + mf * 16 + col];
            float c1_ = __cosf(x), s1_ = __sinf(x);
            float c2 = c1_*c1_ - s1_*s1_, s2 = 2.f*c1_*s1_;
            float c4 = c2*c2 - s2*s2,    s4 = 2.f*c2*s2;
            float c8 = c4*c4 - s4*s4,    s8 = 2.f*c4*s4;
            float c12 = c8*c4 - s8*s4,   s12 = c8*s4 + s8*c4;
            float c13 = c12*c1_ - s12*s1_, s13 = c12*s1_ + s12*c1_;
            // R = E1^(4q+1)
            float rc = c1_, rs = s1_;
            float m4c = (q & 1) ? c4 : 1.f, m4s = (q & 1) ? s4 : 0.f;
            cmul(rc, rs, m4c, m4s);
            float m8c = (q & 2) ? c8 : 1.f, m8s = (q & 2) ? s8 : 0.f;
            cmul(rc, rs, m8c, m8s);
            Rc[mf] = rc; Rs[mf] = rs;
            E1c[mf] = c1_; E1s[mf] = s1_;
            E13c[mf] = c13; E13s[mf] = s13;
        }
        for (int c = 0; c < 10; ++c) {
            PACKSTORE(cur);             // vmcnt-waits only on the prefetched chunk
            int ni = i, nc = c + 1;
            if (nc == 10) { nc = 0; ni = i + 1; }
            if (ni < i1) LOAD(ni, nc);  // issue next chunk; lands under MFMAs below
            LGKM0_BAR();
            __builtin_amdgcn_s_setprio(1);
            #pragma unroll
            for (int h = 0; h < 2; ++h) {
                FragU af[4];
                #pragma unroll
                for (int mf = 0; mf < 4; ++mf) {
                    #pragma unroll
                    for (int d = 0; d < 4; ++d) {
                        af[mf].u[d] = pack_trunc2(Rc[mf], Rs[mf]);
                        if (d < 3) cmul(Rc[mf], Rs[mf], E1c[mf], E1s[mf]);
                        else       cmul(Rc[mf], Rs[mf], E13c[mf], E13s[mf]);
                    }
                }
                #pragma unroll
                for (int nf = 0; nf < 4; ++nf) {
                    int addr = (nwb + nf * 16 + col) * 36 + h * 16 + q * 4;
                    FragU bf;
                    bf.q = *(const uint4*)&bs[cur][addr];
                    #pragma unroll
                    for (int mf = 0; mf < 4; ++mf)
                        acc[mf][nf] = __builtin_amdgcn_mfma_f32_16x16x32_bf16(af[mf].v, bf.v, acc[mf][nf], 0, 0, 0);
                }
            }
            __builtin_amdgcn_s_setprio(0);
            cur ^= 1;
        }
    }
    #pragma unroll
    for (int mf = 0; mf < 4; ++mf) {
        int cbase = cwb + mf * 16 + q * 4;
        #pragma unroll
        for (int nf = 0; nf < 4; ++nf) {
            int o = nt * 128 + nwb + nf * 16 + col;
            if (o < 196) {
                #pragma unroll
                for (int r = 0; r < 4; ++r)
                    atomicAdd(&out[((size_t)b * 196 + o) * 256 + cbase + r], acc[mf][nf][r]);
            }
        }
    }
}

// ---------------- fc2 bias epilogue ----------------
__global__ void bias2_kernel(float* __restrict__ out, const float* __restrict__ bias) {
    int idx = blockIdx.x * 256 + threadIdx.x;
    int o = (idx >> 8) % 196;
    out[idx] += bias[o];
}

extern "C" void kernel_launch(void* const* d_in, const int* in_sizes, int n_in,
                              void* d_out, int out_size, void* d_ws, size_t ws_size,
                              hipStream_t stream) {
    const float* x       = (const float*)d_in[0];
    const float* ln1w    = (const float*)d_in[1];
    const float* ln1b    = (const float*)d_in[2];
    const float* fc1c    = (const float*)d_in[3];
    const float* fc1bias = (const float*)d_in[4];
    const float* ln2w    = (const float*)d_in[5];
    const float* ln2b    = (const float*)d_in[6];
    const float* fc2c    = (const float*)d_in[7];
    const float* fc2bias = (const float*)d_in[8];
    float* out = (float*)d_out;

    float* xnT = (float*)d_ws;              // 128*1792 = 229376
    float* h1  = xnT + 229376;              // 1568*256 = 401408
    float* h1n = h1 + 401408;               // 1568*256

    hipMemsetAsync(h1, 0, (size_t)401408 * 4, stream);
    hipMemsetAsync(d_out, 0, (size_t)401408 * 4, stream);

    const int ks1 = 36, ks2 = 16;           // fc1: 504 blocks; fc2: 4*8*16 = 512 blocks
    ln1_kernel<<<1568, 64, 0, stream>>>(x, ln1w, ln1b, xnT);
    fc1_kernel<<<dim3(2, 7, ks1), 256, 0, stream>>>(xnT, fc1c, h1, ks1);
    ln2_kernel<<<1568, 256, 0, stream>>>(h1, fc1bias, ln2w, ln2b, h1n);
    fc2_kernel<<<dim3(4, 8, ks2), 256, 0, stream>>>(h1n, fc2c, out, ks2);
    bias2_kernel<<<1568, 256, 0, stream>>>(out, fc2bias);
}

// Round 8
// 689.302 us; speedup vs baseline: 1.1964x; 1.1964x over previous
//
#include <hip/hip_runtime.h>
#include <math.h>

typedef short short8 __attribute__((ext_vector_type(8)));
typedef float f32x4 __attribute__((ext_vector_type(4)));

#define EPSF 1e-5f

union FragU { uint4 q; unsigned u[4]; short8 v; };

// bf16 truncation pack: (trunc(hi)<<16)|trunc(lo) in one v_perm
__device__ __forceinline__ unsigned pack_trunc2(float lo_val, float hi_val) {
    return __builtin_amdgcn_perm(__float_as_uint(hi_val), __float_as_uint(lo_val), 0x07060302u);
}
__device__ __forceinline__ float trunc_bf(float x) {
    return __uint_as_float(__float_as_uint(x) & 0xFFFF0000u);
}

// Direct global->LDS 16B copy (no VGPR round-trip). LDS dest = wave-uniform base
// + lane*16 (HW). Global src is per-lane.
__device__ __forceinline__ void gload16_lds(const void* g, void* l) {
    __builtin_amdgcn_global_load_lds(
        (const __attribute__((address_space(1))) void*)g,
        (__attribute__((address_space(3))) void*)l, 16, 0, 0);
}

// Phase barrier: waits own prev-chunk loads (issued a full phase ago -> ~free),
// then s_barrier. Two-sided compiler fencing (rule #18): post sched_barrier +
// memory clobber keep consumer ds_reads from hoisting above.
#define PHASE_BAR() do { \
    asm volatile("s_waitcnt vmcnt(0)" ::: "memory"); \
    __builtin_amdgcn_s_barrier(); \
    __builtin_amdgcn_sched_barrier(0); \
    asm volatile("" ::: "memory"); \
} while (0)

// ---------------- LN over 128, writes TRANSPOSED xnT[i][m], m padded to 1792 ----------------
__global__ void ln1_kernel(const float* __restrict__ x, const float* __restrict__ w,
                           const float* __restrict__ b, float* __restrict__ xnT) {
    int r = blockIdx.x;
    int t = threadIdx.x;
    const float* row = x + (size_t)r * 128;
    float v0 = row[t], v1 = row[t + 64];
    float s = v0 + v1, q = v0 * v0 + v1 * v1;
    #pragma unroll
    for (int off = 32; off > 0; off >>= 1) {
        s += __shfl_down(s, off);
        q += __shfl_down(q, off);
    }
    s = __shfl(s, 0); q = __shfl(q, 0);
    float mu = s * (1.f / 128.f);
    float var = q * (1.f / 128.f) - mu * mu;
    float rs = rsqrtf(var + EPSF);
    xnT[(size_t)t * 1792 + r]        = (v0 - mu) * rs * w[t]      + b[t];
    xnT[(size_t)(t + 64) * 1792 + r] = (v1 - mu) * rs * w[t + 64] + b[t + 64];
}

// ---------------- fc1: split-bf16 MFMA. block: m-tile 256 (4 waves x m64), n-tile 128 ----------------
// grid (2, 7, ks1=36). Atomic k-split into h1.  [R6 VERBATIM — verified]
__launch_bounds__(256)
__global__ void fc1_kernel(const float* __restrict__ xnT, const float* __restrict__ coeffs,
                           float* __restrict__ h1, int KS) {
    const int nt = blockIdx.x;
    const int mt = blockIdx.y;
    const int ks = blockIdx.z;
    const int i0 = (ks * 128) / KS, i1 = ((ks + 1) * 128) / KS;
    const int t = threadIdx.x;
    const int wv = t >> 6, ln = t & 63;
    const int q = ln >> 4, col = ln & 15;
    const int mwrow = mt * 256 + wv * 64;

    __shared__ unsigned bhi[128 * 36];
    __shared__ unsigned blo[128 * 36];

    const float* c0 = coeffs;                               // [256][128][300]
    const float* c1 = coeffs + (size_t)256 * 128 * 300;

    f32x4 acc[4][8] = {};

    const int srow = t >> 1;            // staging row 0..127
    const int j0 = (t & 1) * 16;
    const int og = nt * 128 + srow;
    const size_t prow = (size_t)og * 128;

    for (int i = i0; i < i1; ++i) {
        float zu[4];
        #pragma unroll
        for (int mf = 0; mf < 4; ++mf) {
            int m = mwrow + mf * 16 + col;
            zu[mf] = (m < 1568) ? xnT[(size_t)i * 1792 + m] : 0.f;
        }
        const float* p0 = c0 + (prow + i) * 300;
        const float* p1 = c1 + (prow + i) * 300;

        for (int c = 0; c < 10; ++c) {
            __syncthreads();
            {
                unsigned hw[16], lw[16];
                #pragma unroll
                for (int k4 = 0; k4 < 4; ++k4) {
                    int g = c * 32 + j0 + k4 * 4;
                    float w0[4], w1[4];
                    if (g + 4 <= 300) {
                        float4 a = *(const float4*)(p0 + g);
                        float4 bb = *(const float4*)(p1 + g);
                        w0[0]=a.x; w0[1]=a.y; w0[2]=a.z; w0[3]=a.w;
                        w1[0]=bb.x; w1[1]=bb.y; w1[2]=bb.z; w1[3]=bb.w;
                    } else {
                        #pragma unroll
                        for (int e = 0; e < 4; ++e) {
                            int gg = g + e; bool ok = gg < 300;
                            w0[e] = ok ? p0[gg] : 0.f;
                            w1[e] = ok ? p1[gg] : 0.f;
                        }
                    }
                    #pragma unroll
                    for (int e = 0; e < 4; ++e) {
                        hw[k4*4+e] = pack_trunc2(w0[e], w1[e]);
                        lw[k4*4+e] = pack_trunc2(w0[e]-trunc_bf(w0[e]), w1[e]-trunc_bf(w1[e]));
                    }
                }
                int base = srow * 36 + j0;
                *(uint4*)&bhi[base]      = make_uint4(hw[0], hw[1], hw[2], hw[3]);
                *(uint4*)&bhi[base + 4]  = make_uint4(hw[4], hw[5], hw[6], hw[7]);
                *(uint4*)&bhi[base + 8]  = make_uint4(hw[8], hw[9], hw[10], hw[11]);
                *(uint4*)&bhi[base + 12] = make_uint4(hw[12], hw[13], hw[14], hw[15]);
                *(uint4*)&blo[base]      = make_uint4(lw[0], lw[1], lw[2], lw[3]);
                *(uint4*)&blo[base + 4]  = make_uint4(lw[4], lw[5], lw[6], lw[7]);
                *(uint4*)&blo[base + 8]  = make_uint4(lw[8], lw[9], lw[10], lw[11]);
                *(uint4*)&blo[base + 12] = make_uint4(lw[12], lw[13], lw[14], lw[15]);
            }
            __syncthreads();
            #pragma unroll
            for (int h = 0; h < 2; ++h) {
                FragU ah[4], al[4];
                #pragma unroll
                for (int mf = 0; mf < 4; ++mf) {
                    #pragma unroll
                    for (int d = 0; d < 4; ++d) {
                        float kf = (float)(c * 32 + h * 16 + q * 4 + d + 1);
                        float a = zu[mf] * kf;
                        float cv = __cosf(a), sv = __sinf(a);
                        ah[mf].u[d] = pack_trunc2(cv, sv);
                        al[mf].u[d] = pack_trunc2(cv - trunc_bf(cv), sv - trunc_bf(sv));
                    }
                }
                #pragma unroll
                for (int nf = 0; nf < 8; ++nf) {
                    int addr = (nf * 16 + col) * 36 + h * 16 + q * 4;
                    FragU bh, bl;
                    bh.q = *(const uint4*)&bhi[addr];
                    bl.q = *(const uint4*)&blo[addr];
                    #pragma unroll
                    for (int mf = 0; mf < 4; ++mf) {
                        acc[mf][nf] = __builtin_amdgcn_mfma_f32_16x16x32_bf16(ah[mf].v, bh.v, acc[mf][nf], 0, 0, 0);
                        acc[mf][nf] = __builtin_amdgcn_mfma_f32_16x16x32_bf16(ah[mf].v, bl.v, acc[mf][nf], 0, 0, 0);
                        acc[mf][nf] = __builtin_amdgcn_mfma_f32_16x16x32_bf16(al[mf].v, bh.v, acc[mf][nf], 0, 0, 0);
                    }
                }
            }
        }
    }
    // epilogue: atomic k-split accumulation (1568 % 16 == 0 so frag is all-in or all-out)
    #pragma unroll
    for (int mf = 0; mf < 4; ++mf) {
        if (mwrow + mf * 16 >= 1568) continue;
        int mbase = mwrow + mf * 16 + q * 4;
        #pragma unroll
        for (int nf = 0; nf < 8; ++nf) {
            int o = nt * 128 + nf * 16 + col;
            #pragma unroll
            for (int r = 0; r < 4; ++r)
                atomicAdd(&h1[(size_t)(mbase + r) * 256 + o], acc[mf][nf][r]);
        }
    }
}

// ---------------- LN over 256 of (h1 + fc1_bias) -> h1n ----------------
__global__ void ln2_kernel(const float* __restrict__ h1, const float* __restrict__ bias,
                           const float* __restrict__ w, const float* __restrict__ b,
                           float* __restrict__ h1n) {
    int r = blockIdx.x;
    int t = threadIdx.x;
    float v = h1[(size_t)r * 256 + t] + bias[t];
    float s = v, q = v * v;
    #pragma unroll
    for (int off = 32; off > 0; off >>= 1) {
        s += __shfl_down(s, off);
        q += __shfl_down(q, off);
    }
    __shared__ float ss[4], qq[4];
    int wid = t >> 6;
    if ((t & 63) == 0) { ss[wid] = s; qq[wid] = q; }
    __syncthreads();
    float S = ss[0] + ss[1] + ss[2] + ss[3];
    float Q = qq[0] + qq[1] + qq[2] + qq[3];
    float mu = S * (1.f / 256.f);
    float var = Q * (1.f / 256.f) - mu * mu;
    float rs = rsqrtf(var + EPSF);
    h1n[(size_t)r * 256 + t] = (v - mu) * rs * w[t] + b[t];
}

__device__ __forceinline__ void cmul(float& xr, float& xi, float br, float bi) {
    float nr = xr * br - xi * bi;
    float ni = xr * bi + xi * br;
    xr = nr; xi = ni;
}

// ---------------- fc2: bf16 MFMA with global_load_lds staging ----------------
// Block: m-tile 256 (4 waves x c64), n-tile 128. grid (2, 8, ks2=32) = 512 blocks.
// Staging: f32 coeffs -> LDS directly (global_load_lds, zero VGPR cost), double-
// buffered, ONE barrier/phase, vmcnt wait a full phase after issue (~free).
// bf16 packing moved to consumer side (bit-identical pack_trunc2).
// LDS layout per buffer: [plane0 128x32 f32][plane1 ...], rows 128B, XOR-swizzled:
//   writer (linear lane*16): lane l of inst j holds g-chunk ((l&7)^(l>>3))*4
//   reader: phys = row*128 + ((h<<6|q<<4) ^ ((col&7)<<4))  -> 2-way banks (free)
__launch_bounds__(256, 2)
__global__ void fc2_kernel(const float* __restrict__ h1n, const float* __restrict__ coeffs,
                           float* __restrict__ out, int KS) {
    const int nt = blockIdx.x;
    const int b  = blockIdx.y;
    const int ks = blockIdx.z;
    const int i0 = (ks * 196) / KS, i1 = ((ks + 1) * 196) / KS;
    const int t = threadIdx.x;
    const int wv = t >> 6, ln = t & 63;
    const int q = ln >> 4, col = ln & 15;
    const int cwb = wv * 64;

    __shared__ float ldsf[2 * 2 * 4096];    // 2 buf x 2 plane x (128 rows x 32 f32) = 64 KiB
    char* lds_raw = (char*)&ldsf[0];

    const float* d0 = coeffs;                               // [196][196][300]
    const float* d1 = coeffs + (size_t)196 * 196 * 300;

    f32x4 acc[4][8] = {};

    // loader lane constants
    const int rb8  = ln >> 3;                        // 0..7 (row-within-8)
    const int gsub = ((ln & 7) ^ rb8) * 4;           // pre-swizzled g offset (floats)
    const unsigned km = (q == 3) ? 0u : 0xFFFFFFFFu; // c==9 tail kill mask

    auto STAGE = [&](int i, int c, int buf) {
        const int g = c * 32 + gsub;
        const size_t gw = (g + 4 <= 300) ? (size_t)g : 0; // invalid granules: garbage, masked at read
        #pragma unroll
        for (int j = 0; j < 4; ++j) {
            int row = wv * 32 + j * 8 + rb8;
            int og = nt * 128 + row;
            if (og > 195) og = 195;                  // row-OOB: finite garbage, cols discarded
            size_t go = ((size_t)og * 196 + i) * 300 + gw;
            unsigned lo = (unsigned)buf * 32768u + (unsigned)wv * 4096u + (unsigned)j * 1024u;
            gload16_lds(d0 + go, lds_raw + lo);
            gload16_lds(d1 + go, lds_raw + lo + 16384);
        }
    };

    int cur = 0;
    STAGE(i0, 0, 0);                                 // prologue: chunk 0 in flight
    for (int i = i0; i < i1; ++i) {
        // per-m recurrence state: R tracks e^{i n x}, n = current multiplier
        float Rc[4], Rs[4], E1c[4], E1s[4], E13c[4], E13s[4];
        #pragma unroll
        for (int mf = 0; mf < 4; ++mf) {
            float x = h1n[((size_t)b * 196 + i) * 256 + cwb + mf * 16 + col];
            float c1_ = __cosf(x), s1_ = __sinf(x);
            float c2 = c1_*c1_ - s1_*s1_, s2 = 2.f*c1_*s1_;
            float c4 = c2*c2 - s2*s2,    s4 = 2.f*c2*s2;
            float c8 = c4*c4 - s4*s4,    s8 = 2.f*c4*s4;
            float c12 = c8*c4 - s8*s4,   s12 = c8*s4 + s8*c4;
            float c13 = c12*c1_ - s12*s1_, s13 = c12*s1_ + s12*c1_;
            // R = E1^(4q+1)
            float rc = c1_, rs = s1_;
            float m4c = (q & 1) ? c4 : 1.f, m4s = (q & 1) ? s4 : 0.f;
            cmul(rc, rs, m4c, m4s);
            float m8c = (q & 2) ? c8 : 1.f, m8s = (q & 2) ? s8 : 0.f;
            cmul(rc, rs, m8c, m8s);
            Rc[mf] = rc; Rs[mf] = rs;
            E1c[mf] = c1_; E1s[mf] = s1_;
            E13c[mf] = c13; E13s[mf] = s13;
        }
        for (int c = 0; c < 10; ++c) {
            PHASE_BAR();                 // prev loads landed (all waves) + compute(k-1) done
            int ni = i, nc = c + 1;
            if (nc == 10) { nc = 0; ni = i + 1; }
            if (ni < i1) STAGE(ni, nc, cur ^ 1);   // issue next chunk; lands under MFMAs
            __builtin_amdgcn_sched_barrier(0);
            __builtin_amdgcn_s_setprio(1);
            #pragma unroll
            for (int h = 0; h < 2; ++h) {
                if (h == 1 && c == 9) continue;    // g >= 304: all-zero B, skip
                FragU af[4];
                #pragma unroll
                for (int mf = 0; mf < 4; ++mf) {
                    #pragma unroll
                    for (int d = 0; d < 4; ++d) {
                        af[mf].u[d] = pack_trunc2(Rc[mf], Rs[mf]);
                        if (d < 3) cmul(Rc[mf], Rs[mf], E1c[mf], E1s[mf]);
                        else       cmul(Rc[mf], Rs[mf], E13c[mf], E13s[mf]);
                    }
                }
                #pragma unroll
                for (int nf = 0; nf < 8; ++nf) {
                    int row = nf * 16 + col;
                    int pb = cur * 32768 + row * 128 + (((h << 6) | (q << 4)) ^ ((col & 7) << 4));
                    float4 f0 = *(const float4*)(lds_raw + pb);
                    float4 f1 = *(const float4*)(lds_raw + pb + 16384);
                    FragU bf;
                    bf.u[0] = pack_trunc2(f0.x, f1.x);
                    bf.u[1] = pack_trunc2(f0.y, f1.y);
                    bf.u[2] = pack_trunc2(f0.z, f1.z);
                    bf.u[3] = pack_trunc2(f0.w, f1.w);
                    if (c == 9) {        // g 300..303 live in q==3 slots: zero them
                        bf.u[0] &= km; bf.u[1] &= km; bf.u[2] &= km; bf.u[3] &= km;
                    }
                    #pragma unroll
                    for (int mf = 0; mf < 4; ++mf)
                        acc[mf][nf] = __builtin_amdgcn_mfma_f32_16x16x32_bf16(af[mf].v, bf.v, acc[mf][nf], 0, 0, 0);
                }
            }
            __builtin_amdgcn_s_setprio(0);
            cur ^= 1;
        }
    }
    #pragma unroll
    for (int mf = 0; mf < 4; ++mf) {
        int cbase = cwb + mf * 16 + q * 4;
        #pragma unroll
        for (int nf = 0; nf < 8; ++nf) {
            int o = nt * 128 + nf * 16 + col;
            if (o < 196) {
                #pragma unroll
                for (int r = 0; r < 4; ++r)
                    atomicAdd(&out[((size_t)b * 196 + o) * 256 + cbase + r], acc[mf][nf][r]);
            }
        }
    }
}

// ---------------- fc2 bias epilogue ----------------
__global__ void bias2_kernel(float* __restrict__ out, const float* __restrict__ bias) {
    int idx = blockIdx.x * 256 + threadIdx.x;
    int o = (idx >> 8) % 196;
    out[idx] += bias[o];
}

extern "C" void kernel_launch(void* const* d_in, const int* in_sizes, int n_in,
                              void* d_out, int out_size, void* d_ws, size_t ws_size,
                              hipStream_t stream) {
    const float* x       = (const float*)d_in[0];
    const float* ln1w    = (const float*)d_in[1];
    const float* ln1b    = (const float*)d_in[2];
    const float* fc1c    = (const float*)d_in[3];
    const float* fc1bias = (const float*)d_in[4];
    const float* ln2w    = (const float*)d_in[5];
    const float* ln2b    = (const float*)d_in[6];
    const float* fc2c    = (const float*)d_in[7];
    const float* fc2bias = (const float*)d_in[8];
    float* out = (float*)d_out;

    float* xnT = (float*)d_ws;              // 128*1792 = 229376
    float* h1  = xnT + 229376;              // 1568*256 = 401408
    float* h1n = h1 + 401408;               // 1568*256

    hipMemsetAsync(h1, 0, (size_t)401408 * 4, stream);
    hipMemsetAsync(d_out, 0, (size_t)401408 * 4, stream);

    const int ks1 = 36, ks2 = 32;           // 504 / 512 blocks (2/CU)
    ln1_kernel<<<1568, 64, 0, stream>>>(x, ln1w, ln1b, xnT);
    fc1_kernel<<<dim3(2, 7, ks1), 256, 0, stream>>>(xnT, fc1c, h1, ks1);
    ln2_kernel<<<1568, 256, 0, stream>>>(h1, fc1bias, ln2w, ln2b, h1n);
    fc2_kernel<<<dim3(2, 8, ks2), 256, 0, stream>>>(h1n, fc2c, out, ks2);
    bias2_kernel<<<1568, 256, 0, stream>>>(out, fc2bias);
}